// Round 22
// baseline (145.506 us; speedup 1.0000x reference)
//
#include <hip/hip_runtime.h>
#include <math.h>

typedef __attribute__((ext_vector_type(8))) short short8;
typedef __attribute__((ext_vector_type(4))) float float4v;

__device__ __forceinline__ unsigned short f2bf(float f) {
    unsigned int u = __builtin_bit_cast(unsigned int, f);
    u += 0x7fffu + ((u >> 16) & 1u);
    return (unsigned short)(u >> 16);
}
__device__ __forceinline__ float bf2f(unsigned short h) {
    unsigned int u = ((unsigned int)h) << 16;
    return __builtin_bit_cast(float, u);
}
__device__ __forceinline__ float i2f(int i) { return __builtin_bit_cast(float, i); }
__device__ __forceinline__ int f2i(float f) { return __builtin_bit_cast(int, f); }

#define KCH 32

// ---------- kernel 1: prologue (castW1|castW2|tr_fc) blocks, then scan blocks ----------
// scan: 2 points per thread (independent chains -> ILP); candidates LDS-broadcast.
// cand record layout: [KCH][N][8] floats = {d0,d1,d2,i0,i1,i2,pad,pad} (32B/record)
__global__ __launch_bounds__(256) void scan_pro_kernel(
    const float* __restrict__ W1, const float* __restrict__ W2,
    unsigned short* __restrict__ W1h, unsigned short* __restrict__ W2h,
    const float* __restrict__ fc, unsigned short* __restrict__ fcT,
    const float* __restrict__ xyzf, const float* __restrict__ xyzc,
    float4* __restrict__ cand,             // [KCH][N][2] float4
    int N, int M, int Cc, int nW1, int nW2, int nTR, int Mb) {
    __shared__ float4 smem4[1040];           // 16640 B: tr_fc tile or scan candidates
    int b = blockIdx.x, tid = threadIdx.x;
    int nPro = nW1 + nW2 + nTR;
    if (b < nW1) {
        int q = b * 256 + tid;
        float4 v = ((const float4*)W1)[q];
        ushort4 o; o.x = f2bf(v.x); o.y = f2bf(v.y); o.z = f2bf(v.z); o.w = f2bf(v.w);
        ((ushort4*)W1h)[q] = o;
    } else if (b < nW1 + nW2) {
        int q = (b - nW1) * 256 + tid;
        float4 v = ((const float4*)W2)[q];
        ushort4 o; o.x = f2bf(v.x); o.y = f2bf(v.y); o.z = f2bf(v.z); o.w = f2bf(v.w);
        ((ushort4*)W2h)[q] = o;
    } else if (b < nPro) {
        float (*t)[65] = (float(*)[65])smem4;
        int b2 = b - nW1 - nW2;
        int jb = b2 % Mb, cb = b2 / Mb;
        int j0 = jb * 64, c0 = cb * 64;
        int tx = tid & 63, ty = tid >> 6;
#pragma unroll
        for (int i = 0; i < 16; ++i)
            t[ty + 4 * i][tx] = fc[(size_t)(c0 + ty + 4 * i) * M + j0 + tx];
        __syncthreads();
#pragma unroll
        for (int i = 0; i < 16; ++i)
            fcT[(size_t)(j0 + ty + 4 * i) * Cc + c0 + tx] = f2bf(t[tx][ty + 4 * i]);
    } else {
        // ---- kNN scan: 2 points/thread, LDS-staged candidates, min/med3 top-3 ----
        float4* cl = smem4;                  // first 2 KB
        int b2 = b - nPro;
        int nb = b2 & 31;                    // 32 n-blocks of 512 points
        int ch = b2 >> 5;                    // KCH chunks
        int cs = M / KCH;                    // 128
        int j0 = ch * cs;
        if (tid < cs) {
            int j = j0 + tid;
            float cx = xyzc[j], cy = xyzc[M + j], cz = xyzc[2 * M + j];
            float cc = __fadd_rn(__fadd_rn(__fmul_rn(cx, cx), __fmul_rn(cy, cy)), __fmul_rn(cz, cz));
            cl[tid] = make_float4(cx, cy, cz, cc);
        }
        __syncthreads();
        int nA = nb * 512 + tid;
        int nB = nA + 256;
        float qxA = xyzf[nA], qyA = xyzf[N + nA], qzA = xyzf[2 * N + nA];
        float qxB = xyzf[nB], qyB = xyzf[N + nB], qzB = xyzf[2 * N + nB];
        float qqA = __fadd_rn(__fadd_rn(__fmul_rn(qxA, qxA), __fmul_rn(qyA, qyA)), __fmul_rn(qzA, qzA));
        float qqB = __fadd_rn(__fadd_rn(__fmul_rn(qxB, qxB), __fmul_rn(qyB, qyB)), __fmul_rn(qzB, qzB));
        float dA0 = INFINITY, dA1 = INFINITY, dA2 = INFINITY;
        float dB0 = INFINITY, dB1 = INFINITY, dB2 = INFINITY;
        int iA0 = 0x7fffffff, iA1 = 0x7fffffff, iA2 = 0x7fffffff;
        int iB0 = 0x7fffffff, iB1 = 0x7fffffff, iB2 = 0x7fffffff;
#pragma unroll 8
        for (int jj = 0; jj < cs; ++jj) {
            float4 c = cl[jj];               // broadcast; shared by both points
            int j = j0 + jj;
            // point A chain (sequence identical to single-point version)
            float sA  = fmaf(qzA, c.z, fmaf(qyA, c.y, __fmul_rn(qxA, c.x)));
            float ddA = __fadd_rn(__fsub_rn(qqA, 2.f * sA), c.w);
            // point B chain (independent -> fills A's dependency stalls)
            float sB  = fmaf(qzB, c.z, fmaf(qyB, c.y, __fmul_rn(qxB, c.x)));
            float ddB = __fadd_rn(__fsub_rn(qqB, 2.f * sB), c.w);
            bool aA0 = ddA < dA0, aA1 = ddA < dA1, aA2 = ddA < dA2;
            float nA0 = fminf(ddA, dA0);
            float nA1 = __builtin_amdgcn_fmed3f(dA0, dA1, ddA);
            float nA2 = __builtin_amdgcn_fmed3f(dA1, dA2, ddA);
            iA2 = aA1 ? iA1 : (aA2 ? j : iA2);
            iA1 = aA0 ? iA0 : (aA1 ? j : iA1);
            iA0 = aA0 ? j : iA0;
            dA0 = nA0; dA1 = nA1; dA2 = nA2;
            bool aB0 = ddB < dB0, aB1 = ddB < dB1, aB2 = ddB < dB2;
            float nB0 = fminf(ddB, dB0);
            float nB1 = __builtin_amdgcn_fmed3f(dB0, dB1, ddB);
            float nB2 = __builtin_amdgcn_fmed3f(dB1, dB2, ddB);
            iB2 = aB1 ? iB1 : (aB2 ? j : iB2);
            iB1 = aB0 ? iB0 : (aB1 ? j : iB1);
            iB0 = aB0 ? j : iB0;
            dB0 = nB0; dB1 = nB1; dB2 = nB2;
        }
        size_t recA = ((size_t)ch * N + nA) * 2;
        cand[recA]     = make_float4(dA0, dA1, dA2, i2f(iA0));
        cand[recA + 1] = make_float4(i2f(iA1), i2f(iA2), 0.f, 0.f);
        size_t recB = ((size_t)ch * N + nB) * 2;
        cand[recB]     = make_float4(dB0, dB1, dB2, i2f(iB0));
        cand[recB + 1] = make_float4(i2f(iB1), i2f(iB2), 0.f, 0.f);
    }
}

// ---------- kernel 2: merge blocks first, then tr_ff blocks (independent) ----------
__global__ __launch_bounds__(256) void merge_trff_kernel(
    const float4* __restrict__ cand,
    const float* __restrict__ xyzf, const float* __restrict__ xyzc,
    const float* __restrict__ ff, unsigned short* __restrict__ xbuf,
    int* __restrict__ idx3, float* __restrict__ w3,
    int N, int M, int Cin, int Cc, int nMerge, int Nb) {
    __shared__ float t[64][65];
    int b = blockIdx.x, tid = threadIdx.x;
    if (b < nMerge) {
        int n = b * 256 + tid;
        float bd0 = INFINITY, bd1 = INFINITY, bd2 = INFINITY;
        int bi0 = 0x7fffffff, bi1 = 0x7fffffff, bi2 = 0x7fffffff;
#pragma unroll
        for (int chg = 0; chg < KCH / 4; ++chg) {
            float4 ra[4], rb[4];
#pragma unroll
            for (int k = 0; k < 4; ++k) {
                size_t rec = ((size_t)(chg * 4 + k) * N + n) * 2;
                ra[k] = cand[rec];
                rb[k] = cand[rec + 1];
            }
#pragma unroll
            for (int k = 0; k < 4; ++k) {
                float dv[3] = {ra[k].x, ra[k].y, ra[k].z};
                int iv[3] = {f2i(ra[k].w), f2i(rb[k].x), f2i(rb[k].y)};
#pragma unroll
                for (int e = 0; e < 3; ++e) {
                    float d = dv[e]; int i = iv[e];
                    if (d < bd2 || (d == bd2 && i < bi2)) {
                        if (d < bd1 || (d == bd1 && i < bi1)) {
                            bd2 = bd1; bi2 = bi1;
                            if (d < bd0 || (d == bd0 && i < bi0)) { bd1 = bd0; bi1 = bi0; bd0 = d; bi0 = i; }
                            else                                  { bd1 = d; bi1 = i; }
                        } else { bd2 = d; bi2 = i; }
                    }
                }
            }
        }
        float qx = xyzf[n], qy = xyzf[N + n], qz = xyzf[2 * N + n];
        int iif[3] = {bi0, bi1, bi2};
        float u[3];
#pragma unroll
        for (int s = 0; s < 3; ++s) {
            int i = iif[s];
            float cx = xyzc[i], cy = xyzc[M + i], cz = xyzc[2 * M + i];
            float dx = __fsub_rn(qx, cx), dy = __fsub_rn(qy, cy), dz = __fsub_rn(qz, cz);
            float dd = __fadd_rn(__fadd_rn(__fmul_rn(dx, dx), __fmul_rn(dy, dy)), __fmul_rn(dz, dz));
            float dist = fmaxf(sqrtf(dd), 1e-8f);
            u[s] = 1.f / dist;
        }
        float su = __fadd_rn(__fadd_rn(u[0], u[1]), u[2]);
#pragma unroll
        for (int s = 0; s < 3; ++s) {
            idx3[n * 3 + s] = iif[s];
            w3[n * 3 + s] = u[s] / su;
        }
    } else {
        int b2 = b - nMerge;
        int nb = b2 % Nb, cb = b2 / Nb;
        int n0 = nb * 64, c0 = cb * 64;
        int tx = tid & 63, ty = tid >> 6;
#pragma unroll
        for (int i = 0; i < 16; ++i)
            t[ty + 4 * i][tx] = ff[(size_t)(c0 + ty + 4 * i) * N + n0 + tx];
        __syncthreads();
#pragma unroll
        for (int i = 0; i < 16; ++i)
            xbuf[(size_t)(n0 + ty + 4 * i) * Cin + Cc + c0 + tx] = f2bf(t[tx][ty + 4 * i]);
    }
}

// ---------- interp (vectorized 8 ch/thread): xbuf[n][c..c+7] = sum_s w_s*fcT[i_s][c..c+7] ----------
__global__ __launch_bounds__(256) void interp_kernel(
    const unsigned short* __restrict__ fcT, const int* __restrict__ idx3,
    const float* __restrict__ w3, unsigned short* __restrict__ xbuf,
    int Cin, int Cc) {
    int tid = threadIdx.x;
    int ploc = tid >> 6, cs = tid & 63;      // 4 points/block, 64 chan-slots
    int n = blockIdx.x * 4 + ploc;
    int c = cs * 8;
    int i0 = idx3[n * 3], i1 = idx3[n * 3 + 1], i2 = idx3[n * 3 + 2];
    float w0 = w3[n * 3], w1 = w3[n * 3 + 1], w2 = w3[n * 3 + 2];
    short8 f0 = *(const short8*)(const void*)&fcT[(size_t)i0 * Cc + c];
    short8 f1 = *(const short8*)(const void*)&fcT[(size_t)i1 * Cc + c];
    short8 f2v = *(const short8*)(const void*)&fcT[(size_t)i2 * Cc + c];
    short8 o;
#pragma unroll
    for (int j = 0; j < 8; ++j) {
        float a = bf2f((unsigned short)f0[j]);
        float bb = bf2f((unsigned short)f1[j]);
        float cc = bf2f((unsigned short)f2v[j]);
        float v = fmaf(w2, cc, fmaf(w1, bb, w0 * a));
        o[j] = (short)f2bf(v);
    }
    *(short8*)(void*)&xbuf[(size_t)n * Cin + c] = o;
}

// ---------- bf16 MFMA GEMM (BK=128, four 32-wide panels) + channel partials ----------
template <int TRANS>
__global__ __launch_bounds__(256) void gemm_bf16_kernel(
    const unsigned short* __restrict__ A,  // [O][K] bf16
    const unsigned short* __restrict__ B,  // [Ntot][K] bf16
    unsigned short* __restrict__ Dt,       // TRANS? [Ntot][O] : [O][Ntot]
    float* __restrict__ psumG,             // [Ntot/128][O]
    float* __restrict__ psqG,              // [Ntot/128][O]
    int K, int Ntot, int O) {
    __shared__ short As[4 * 128 * 32], Bs[4 * 128 * 32];   // 4 panels x [128][32], 64 KB
    int tid = threadIdx.x;
    int lane = tid & 63, wid = tid >> 6;
    int wm = wid & 1, wn = wid >> 1;
    int o0 = blockIdx.y * 128, n0 = blockIdx.x * 128;
    int r16 = lane & 15, kg = lane >> 4;
    float4v acc[4][4];
#pragma unroll
    for (int a = 0; a < 4; ++a)
#pragma unroll
        for (int b = 0; b < 4; ++b)
            acc[a][b] = (float4v){0.f, 0.f, 0.f, 0.f};
    for (int k0 = 0; k0 < K; k0 += 128) {
#pragma unroll
        for (int h = 0; h < 8; ++h) {
            int ch = tid + h * 256;
            int panel = ch >> 9, within = ch & 511;
            int row = within >> 2, kq = within & 3;
            int koff = k0 + panel * 32 + kq * 8;
            __builtin_amdgcn_global_load_lds(
                (const __attribute__((address_space(1))) void*)(A + (size_t)(o0 + row) * K + koff),
                (__attribute__((address_space(3))) void*)&As[ch * 8], 16, 0, 0);
            __builtin_amdgcn_global_load_lds(
                (const __attribute__((address_space(1))) void*)(B + (size_t)(n0 + row) * K + koff),
                (__attribute__((address_space(3))) void*)&Bs[ch * 8], 16, 0, 0);
        }
        __syncthreads();
#pragma unroll
        for (int kkp = 0; kkp < 4; ++kkp) {
            short8 af[4], bfr[4];
#pragma unroll
            for (int mi = 0; mi < 4; ++mi)
                af[mi] = *(const short8*)(const void*)&As[kkp * 4096 + (wm * 64 + mi * 16 + r16) * 32 + kg * 8];
#pragma unroll
            for (int ni = 0; ni < 4; ++ni)
                bfr[ni] = *(const short8*)(const void*)&Bs[kkp * 4096 + (wn * 64 + ni * 16 + r16) * 32 + kg * 8];
#pragma unroll
            for (int mi = 0; mi < 4; ++mi)
#pragma unroll
                for (int ni = 0; ni < 4; ++ni)
                    acc[mi][ni] = __builtin_amdgcn_mfma_f32_16x16x32_bf16(af[mi], bfr[ni], acc[mi][ni], 0, 0, 0);
        }
        __syncthreads();
    }
    if (TRANS) {
#pragma unroll
        for (int mi = 0; mi < 4; ++mi) {
            int obase = o0 + wm * 64 + mi * 16 + kg * 4;
#pragma unroll
            for (int ni = 0; ni < 4; ++ni) {
                int n = n0 + wn * 64 + ni * 16 + r16;
                ushort4 pk;
                pk.x = f2bf(acc[mi][ni][0]);
                pk.y = f2bf(acc[mi][ni][1]);
                pk.z = f2bf(acc[mi][ni][2]);
                pk.w = f2bf(acc[mi][ni][3]);
                *(ushort4*)(void*)&Dt[(size_t)n * O + obase] = pk;
            }
        }
    } else {
#pragma unroll
        for (int mi = 0; mi < 4; ++mi) {
            int obase = o0 + wm * 64 + mi * 16 + kg * 4;
#pragma unroll
            for (int ni = 0; ni < 4; ++ni) {
                int col = n0 + wn * 64 + ni * 16 + r16;
#pragma unroll
                for (int r = 0; r < 4; ++r)
                    Dt[(size_t)(obase + r) * Ntot + col] = f2bf(acc[mi][ni][r]);
            }
        }
    }
    float2* red = (float2*)As;
#pragma unroll
    for (int mi = 0; mi < 4; ++mi) {
#pragma unroll
        for (int r = 0; r < 4; ++r) {
            float s = 0.f, q = 0.f;
#pragma unroll
            for (int ni = 0; ni < 4; ++ni) {
                float v = acc[mi][ni][r];
                s += v; q += v * v;
            }
#pragma unroll
            for (int off = 1; off <= 8; off <<= 1) {
                s += __shfl_xor(s, off);
                q += __shfl_xor(q, off);
            }
            if (r16 == 0) {
                int row = wm * 64 + mi * 16 + kg * 4 + r;
                red[row * 2 + wn] = make_float2(s, q);
            }
        }
    }
    __syncthreads();
    if (tid < 128) {
        float2 a = red[tid * 2 + 0], b = red[tid * 2 + 1];
        int o = o0 + tid;
        psumG[(size_t)blockIdx.x * O + o] = a.x + b.x;
        psqG [(size_t)blockIdx.x * O + o] = a.y + b.y;
    }
}

// ---------- layer1 apply: stats-reduce + BN + ReLU in place on y[N][C] bf16 ----------
__global__ __launch_bounds__(256) void bnrelu_ip_kernel(
    unsigned short* __restrict__ Y, const float* __restrict__ psumG, const float* __restrict__ psqG,
    const float* __restrict__ g, const float* __restrict__ b, int Nn, int C, int NB) {
    __shared__ float2 st[4][64];
    __shared__ float2 msr[64], gbl[64];
    int tid = threadIdx.x;
    int n0 = blockIdx.x * 64, o0 = blockIdx.y * 64;
    {
        int ch = tid & 63, q4 = tid >> 6;
        float s = 0.f, qq = 0.f;
        int per = NB / 4;
        for (int i = 0; i < per; ++i) {
            int bx = q4 * per + i;
            s  += psumG[(size_t)bx * C + o0 + ch];
            qq += psqG [(size_t)bx * C + o0 + ch];
        }
        st[q4][ch] = make_float2(s, qq);
    }
    __syncthreads();
    if (tid < 64) {
        float2 a = st[0][tid], b2 = st[1][tid], c2 = st[2][tid], d2 = st[3][tid];
        float S = (a.x + b2.x) + (c2.x + d2.x);
        float Q = (a.y + b2.y) + (c2.y + d2.y);
        float m = S / Nn;
        float v = Q / Nn - m * m;
        msr[tid] = make_float2(m, rsqrtf(v + 1e-5f));
        gbl[tid] = make_float2(g[o0 + tid], b[o0 + tid]);
    }
    __syncthreads();
    int row = tid >> 2, k0 = tid & 3;
#pragma unroll
    for (int j = 0; j < 4; ++j) {
        int k = k0 + 4 * j;
        size_t a = (size_t)(n0 + row) * C + o0 + k * 4;
        ushort4 v = *(const ushort4*)(const void*)&Y[a];
        int ob = k * 4;
        float2 ms0 = msr[ob], ms1 = msr[ob + 1], ms2 = msr[ob + 2], ms3 = msr[ob + 3];
        float2 gb0 = gbl[ob], gb1 = gbl[ob + 1], gb2 = gbl[ob + 2], gb3 = gbl[ob + 3];
        v.x = f2bf(fmaxf(gb0.x * (bf2f(v.x) - ms0.x) * ms0.y + gb0.y, 0.f));
        v.y = f2bf(fmaxf(gb1.x * (bf2f(v.y) - ms1.x) * ms1.y + gb1.y, 0.f));
        v.z = f2bf(fmaxf(gb2.x * (bf2f(v.z) - ms2.x) * ms2.y + gb2.y, 0.f));
        v.w = f2bf(fmaxf(gb3.x * (bf2f(v.w) - ms3.x) * ms3.y + gb3.y, 0.f));
        *(ushort4*)(void*)&Y[a] = v;
    }
}

// ---------- layer2 apply: stats-reduce + BN + ReLU; bf16 D [O][N] -> f32 out ----------
__global__ __launch_bounds__(256) void bnrelu2_kernel(
    const unsigned short* __restrict__ Dh, float* __restrict__ Y,
    const float* __restrict__ psumG, const float* __restrict__ psqG,
    const float* __restrict__ g, const float* __restrict__ b, int Nn, int C, int NB) {
    __shared__ float2 red[128];
    __shared__ float2 ms;
    int c = blockIdx.y, tid = threadIdx.x;
    if (tid < NB)
        red[tid] = make_float2(psumG[(size_t)tid * C + c], psqG[(size_t)tid * C + c]);
    __syncthreads();
    for (int s2 = NB / 2; s2 > 0; s2 >>= 1) {
        if (tid < s2) {
            red[tid].x += red[tid + s2].x;
            red[tid].y += red[tid + s2].y;
        }
        __syncthreads();
    }
    if (tid == 0) {
        float m = red[0].x / Nn;
        ms = make_float2(m, rsqrtf(red[0].y / Nn - m * m + 1e-5f));
    }
    __syncthreads();
    float mm = ms.x, rr = ms.y, gg = g[c], bb = b[c];
    int q = (int)blockIdx.x * 256 + tid;
    ushort4 dv = ((const ushort4*)(Dh + (size_t)c * Nn))[q];
    float4 v;
    v.x = fmaxf(gg * (bf2f(dv.x) - mm) * rr + bb, 0.f);
    v.y = fmaxf(gg * (bf2f(dv.y) - mm) * rr + bb, 0.f);
    v.z = fmaxf(gg * (bf2f(dv.z) - mm) * rr + bb, 0.f);
    v.w = fmaxf(gg * (bf2f(dv.w) - mm) * rr + bb, 0.f);
    ((float4*)Y)[(size_t)c * (Nn >> 2) + q] = v;
}

extern "C" void kernel_launch(void* const* d_in, const int* in_sizes, int n_in,
                              void* d_out, int out_size, void* d_ws, size_t ws_size,
                              hipStream_t stream) {
    const float* xyzf = (const float*)d_in[0];
    const float* xyzc = (const float*)d_in[1];
    const float* ff   = (const float*)d_in[2];
    const float* fc   = (const float*)d_in[3];
    const float* W1   = (const float*)d_in[4];
    const float* g1   = (const float*)d_in[5];
    const float* b1   = (const float*)d_in[6];
    const float* W2   = (const float*)d_in[7];
    const float* g2   = (const float*)d_in[8];
    const float* b2   = (const float*)d_in[9];

    int N  = in_sizes[0] / 3;       // 16384
    int M  = in_sizes[1] / 3;       // 4096
    int Cf = in_sizes[2] / N;       // 256
    int Cc = in_sizes[3] / M;       // 512
    int h1 = in_sizes[5];           // 512
    int h2 = in_sizes[8];           // 512
    int Cin = Cc + Cf;              // 768
    float* out = (float*)d_out;

    // workspace carve (~48 MB)
    char* p = (char*)d_ws;
    unsigned short* W1h = (unsigned short*)p; p += (size_t)h1 * Cin * 2;
    unsigned short* W2h = (unsigned short*)p; p += (size_t)h2 * h1 * 2;
    unsigned short* fcT = (unsigned short*)p; p += (size_t)M * Cc * 2;
    int*   idx3 = (int*)p;   p += (size_t)N * 3 * sizeof(int);
    float* w3   = (float*)p; p += (size_t)N * 3 * sizeof(float);
    int NB = N / 128;                                   // 128 GEMM n-blocks
    float* psumG = (float*)p; p += (size_t)NB * h1 * sizeof(float);
    float* psqG  = (float*)p; p += (size_t)NB * h1 * sizeof(float);
    unsigned short* d1h = (unsigned short*)p; p += (size_t)h1 * N * 2;   // y-layout [N][h1] bf16
    unsigned short* xbuf = (unsigned short*)p; p += (size_t)N * Cin * 2;
    // cand records alias d1h: 32B x KCH x N = 16.78 MB = exactly |d1h|.
    float4* cand = (float4*)d1h;
    unsigned short* d2h = xbuf;                         // gemm2 D [h2][N] bf16 (xbuf dead post-gemm1)

    // 1. prologue + kNN scan (2 pts/thread; prologue blocks first)
    int nW1 = h1 * Cin / 1024, nW2 = h2 * h1 / 1024;
    int Mb = M / 64, nTR = Mb * (Cc / 64);
    int nPro = nW1 + nW2 + nTR;
    scan_pro_kernel<<<nPro + (N / 512) * KCH, 256, 0, stream>>>(
        W1, W2, W1h, W2h, fc, fcT, xyzf, xyzc, cand,
        N, M, Cc, nW1, nW2, nTR, Mb);

    // 2. merge + tr_ff (independent; merge blocks first)
    int nMerge = N / 256, Nb = N / 64, nTF = Nb * (Cf / 64);
    merge_trff_kernel<<<nMerge + nTF, 256, 0, stream>>>(
        cand, xyzf, xyzc, ff, xbuf, idx3, w3, N, M, Cin, Cc, nMerge, Nb);

    // 3. interp (8 channels/thread; 4 points/block)
    interp_kernel<<<N / 4, 256, 0, stream>>>(fcT, idx3, w3, xbuf, Cin, Cc);

    // 4-5. layer 1: gemm1 writes y-layout [N][h1] into d1h; bn1 in place
    gemm_bf16_kernel<1><<<dim3(N / 128, h1 / 128), 256, 0, stream>>>(
        W1h, xbuf, d1h, psumG, psqG, Cin, N, h1);
    bnrelu_ip_kernel<<<dim3(N / 64, h1 / 64), 256, 0, stream>>>(
        d1h, psumG, psqG, g1, b1, N, h1, NB);

    // 6-7. layer 2: gemm2 reads d1h as B, writes [h2][N] into xbuf; bn2 -> out
    gemm_bf16_kernel<0><<<dim3(N / 128, h2 / 128), 256, 0, stream>>>(
        W2h, d1h, d2h, psumG, psqG, h1, N, h2);
    bnrelu2_kernel<<<dim3(N / 1024, h2), 256, 0, stream>>>(
        d2h, out, psumG, psqG, g2, b2, N, h2, NB);
}

// Round 23
// 129.640 us; speedup vs baseline: 1.1224x; 1.1224x over previous
//
#include <hip/hip_runtime.h>
#include <math.h>

typedef __attribute__((ext_vector_type(8))) short short8;
typedef __attribute__((ext_vector_type(4))) float float4v;

__device__ __forceinline__ unsigned short f2bf(float f) {
    unsigned int u = __builtin_bit_cast(unsigned int, f);
    u += 0x7fffu + ((u >> 16) & 1u);
    return (unsigned short)(u >> 16);
}
__device__ __forceinline__ float bf2f(unsigned short h) {
    unsigned int u = ((unsigned int)h) << 16;
    return __builtin_bit_cast(float, u);
}
__device__ __forceinline__ float i2f(int i) { return __builtin_bit_cast(float, i); }
__device__ __forceinline__ int f2i(float f) { return __builtin_bit_cast(int, f); }

#define KCH 32

// ---------- kernel 1: prologue (castW1|castW2|tr_fc) blocks, then scan blocks ----------
// scan: 1 point/thread (2048 blocks -> max TLP; r22 showed 2pt/thread trades TLP
// for ILP at a net loss). cand record: [KCH][N][8] floats {d0,d1,d2,i0,i1,i2,pad,pad}.
__global__ __launch_bounds__(256) void scan_pro_kernel(
    const float* __restrict__ W1, const float* __restrict__ W2,
    unsigned short* __restrict__ W1h, unsigned short* __restrict__ W2h,
    const float* __restrict__ fc, unsigned short* __restrict__ fcT,
    const float* __restrict__ xyzf, const float* __restrict__ xyzc,
    float4* __restrict__ cand,             // [KCH][N][2] float4
    int N, int M, int Cc, int nW1, int nW2, int nTR, int Mb) {
    __shared__ float4 smem4[1040];           // 16640 B: tr_fc tile or scan candidates
    int b = blockIdx.x, tid = threadIdx.x;
    int nPro = nW1 + nW2 + nTR;
    if (b < nW1) {
        int q = b * 256 + tid;
        float4 v = ((const float4*)W1)[q];
        ushort4 o; o.x = f2bf(v.x); o.y = f2bf(v.y); o.z = f2bf(v.z); o.w = f2bf(v.w);
        ((ushort4*)W1h)[q] = o;
    } else if (b < nW1 + nW2) {
        int q = (b - nW1) * 256 + tid;
        float4 v = ((const float4*)W2)[q];
        ushort4 o; o.x = f2bf(v.x); o.y = f2bf(v.y); o.z = f2bf(v.z); o.w = f2bf(v.w);
        ((ushort4*)W2h)[q] = o;
    } else if (b < nPro) {
        float (*t)[65] = (float(*)[65])smem4;
        int b2 = b - nW1 - nW2;
        int jb = b2 % Mb, cb = b2 / Mb;
        int j0 = jb * 64, c0 = cb * 64;
        int tx = tid & 63, ty = tid >> 6;
#pragma unroll
        for (int i = 0; i < 16; ++i)
            t[ty + 4 * i][tx] = fc[(size_t)(c0 + ty + 4 * i) * M + j0 + tx];
        __syncthreads();
#pragma unroll
        for (int i = 0; i < 16; ++i)
            fcT[(size_t)(j0 + ty + 4 * i) * Cc + c0 + tx] = f2bf(t[tx][ty + 4 * i]);
    } else {
        // ---- kNN scan: LDS-staged candidates (broadcast reads), min/med3 top-3 ----
        float4* cl = smem4;                  // first 2 KB
        int b2 = b - nPro;
        int n = (b2 & 63) * 256 + tid;       // 64 n-blocks
        int ch = b2 >> 6;                    // KCH chunks
        int cs = M / KCH;                    // 128
        int j0 = ch * cs;
        if (tid < cs) {
            int j = j0 + tid;
            float cx = xyzc[j], cy = xyzc[M + j], cz = xyzc[2 * M + j];
            float cc = __fadd_rn(__fadd_rn(__fmul_rn(cx, cx), __fmul_rn(cy, cy)), __fmul_rn(cz, cz));
            cl[tid] = make_float4(cx, cy, cz, cc);
        }
        __syncthreads();
        float qx = xyzf[n], qy = xyzf[N + n], qz = xyzf[2 * N + n];
        float qq = __fadd_rn(__fadd_rn(__fmul_rn(qx, qx), __fmul_rn(qy, qy)), __fmul_rn(qz, qz));
        float d0 = INFINITY, d1 = INFINITY, d2 = INFINITY;
        int i0 = 0x7fffffff, i1 = 0x7fffffff, i2 = 0x7fffffff;
#pragma unroll 8
        for (int jj = 0; jj < cs; ++jj) {
            float4 c = cl[jj];               // same addr all lanes -> LDS broadcast
            int j = j0 + jj;
            float s  = fmaf(qz, c.z, fmaf(qy, c.y, __fmul_rn(qx, c.x)));
            float dd = __fadd_rn(__fsub_rn(qq, 2.f * s), c.w);
            bool a0 = dd < d0, a1 = dd < d1, a2 = dd < d2;
            float nd0 = fminf(dd, d0);
            float nd1 = __builtin_amdgcn_fmed3f(d0, d1, dd);
            float nd2 = __builtin_amdgcn_fmed3f(d1, d2, dd);
            i2 = a1 ? i1 : (a2 ? j : i2);
            i1 = a0 ? i0 : (a1 ? j : i1);
            i0 = a0 ? j : i0;
            d0 = nd0; d1 = nd1; d2 = nd2;
        }
        size_t rec = ((size_t)ch * N + n) * 2;
        cand[rec]     = make_float4(d0, d1, d2, i2f(i0));
        cand[rec + 1] = make_float4(i2f(i1), i2f(i2), 0.f, 0.f);
    }
}

// ---------- kernel 2: merge blocks first, then tr_ff blocks (independent) ----------
__global__ __launch_bounds__(256) void merge_trff_kernel(
    const float4* __restrict__ cand,
    const float* __restrict__ xyzf, const float* __restrict__ xyzc,
    const float* __restrict__ ff, unsigned short* __restrict__ xbuf,
    int* __restrict__ idx3, float* __restrict__ w3,
    int N, int M, int Cin, int Cc, int nMerge, int Nb) {
    __shared__ float t[64][65];
    int b = blockIdx.x, tid = threadIdx.x;
    if (b < nMerge) {
        int n = b * 256 + tid;
        float bd0 = INFINITY, bd1 = INFINITY, bd2 = INFINITY;
        int bi0 = 0x7fffffff, bi1 = 0x7fffffff, bi2 = 0x7fffffff;
#pragma unroll
        for (int chg = 0; chg < KCH / 4; ++chg) {
            float4 ra[4], rb[4];
#pragma unroll
            for (int k = 0; k < 4; ++k) {
                size_t rec = ((size_t)(chg * 4 + k) * N + n) * 2;
                ra[k] = cand[rec];
                rb[k] = cand[rec + 1];
            }
#pragma unroll
            for (int k = 0; k < 4; ++k) {
                float dv[3] = {ra[k].x, ra[k].y, ra[k].z};
                int iv[3] = {f2i(ra[k].w), f2i(rb[k].x), f2i(rb[k].y)};
#pragma unroll
                for (int e = 0; e < 3; ++e) {
                    float d = dv[e]; int i = iv[e];
                    if (d < bd2 || (d == bd2 && i < bi2)) {
                        if (d < bd1 || (d == bd1 && i < bi1)) {
                            bd2 = bd1; bi2 = bi1;
                            if (d < bd0 || (d == bd0 && i < bi0)) { bd1 = bd0; bi1 = bi0; bd0 = d; bi0 = i; }
                            else                                  { bd1 = d; bi1 = i; }
                        } else { bd2 = d; bi2 = i; }
                    }
                }
            }
        }
        float qx = xyzf[n], qy = xyzf[N + n], qz = xyzf[2 * N + n];
        int iif[3] = {bi0, bi1, bi2};
        float u[3];
#pragma unroll
        for (int s = 0; s < 3; ++s) {
            int i = iif[s];
            float cx = xyzc[i], cy = xyzc[M + i], cz = xyzc[2 * M + i];
            float dx = __fsub_rn(qx, cx), dy = __fsub_rn(qy, cy), dz = __fsub_rn(qz, cz);
            float dd = __fadd_rn(__fadd_rn(__fmul_rn(dx, dx), __fmul_rn(dy, dy)), __fmul_rn(dz, dz));
            float dist = fmaxf(sqrtf(dd), 1e-8f);
            u[s] = 1.f / dist;
        }
        float su = __fadd_rn(__fadd_rn(u[0], u[1]), u[2]);
#pragma unroll
        for (int s = 0; s < 3; ++s) {
            idx3[n * 3 + s] = iif[s];
            w3[n * 3 + s] = u[s] / su;
        }
    } else {
        int b2 = b - nMerge;
        int nb = b2 % Nb, cb = b2 / Nb;
        int n0 = nb * 64, c0 = cb * 64;
        int tx = tid & 63, ty = tid >> 6;
#pragma unroll
        for (int i = 0; i < 16; ++i)
            t[ty + 4 * i][tx] = ff[(size_t)(c0 + ty + 4 * i) * N + n0 + tx];
        __syncthreads();
#pragma unroll
        for (int i = 0; i < 16; ++i)
            xbuf[(size_t)(n0 + ty + 4 * i) * Cin + Cc + c0 + tx] = f2bf(t[tx][ty + 4 * i]);
    }
}

// ---------- interp (vectorized 8 ch/thread): xbuf[n][c..c+7] = sum_s w_s*fcT[i_s][c..c+7] ----------
__global__ __launch_bounds__(256) void interp_kernel(
    const unsigned short* __restrict__ fcT, const int* __restrict__ idx3,
    const float* __restrict__ w3, unsigned short* __restrict__ xbuf,
    int Cin, int Cc) {
    int tid = threadIdx.x;
    int ploc = tid >> 6, cs = tid & 63;      // 4 points/block, 64 chan-slots
    int n = blockIdx.x * 4 + ploc;
    int c = cs * 8;
    int i0 = idx3[n * 3], i1 = idx3[n * 3 + 1], i2 = idx3[n * 3 + 2];
    float w0 = w3[n * 3], w1 = w3[n * 3 + 1], w2 = w3[n * 3 + 2];
    short8 f0 = *(const short8*)(const void*)&fcT[(size_t)i0 * Cc + c];
    short8 f1 = *(const short8*)(const void*)&fcT[(size_t)i1 * Cc + c];
    short8 f2v = *(const short8*)(const void*)&fcT[(size_t)i2 * Cc + c];
    short8 o;
#pragma unroll
    for (int j = 0; j < 8; ++j) {
        float a = bf2f((unsigned short)f0[j]);
        float bb = bf2f((unsigned short)f1[j]);
        float cc = bf2f((unsigned short)f2v[j]);
        float v = fmaf(w2, cc, fmaf(w1, bb, w0 * a));
        o[j] = (short)f2bf(v);
    }
    *(short8*)(void*)&xbuf[(size_t)n * Cin + c] = o;
}

// ---------- bf16 MFMA GEMM (BK=128, four 32-wide panels) + channel partials ----------
template <int TRANS>
__global__ __launch_bounds__(256) void gemm_bf16_kernel(
    const unsigned short* __restrict__ A,  // [O][K] bf16
    const unsigned short* __restrict__ B,  // [Ntot][K] bf16
    unsigned short* __restrict__ Dt,       // TRANS? [Ntot][O] : [O][Ntot]
    float* __restrict__ psumG,             // [Ntot/128][O]
    float* __restrict__ psqG,              // [Ntot/128][O]
    int K, int Ntot, int O) {
    __shared__ short As[4 * 128 * 32], Bs[4 * 128 * 32];   // 4 panels x [128][32], 64 KB
    int tid = threadIdx.x;
    int lane = tid & 63, wid = tid >> 6;
    int wm = wid & 1, wn = wid >> 1;
    int o0 = blockIdx.y * 128, n0 = blockIdx.x * 128;
    int r16 = lane & 15, kg = lane >> 4;
    float4v acc[4][4];
#pragma unroll
    for (int a = 0; a < 4; ++a)
#pragma unroll
        for (int b = 0; b < 4; ++b)
            acc[a][b] = (float4v){0.f, 0.f, 0.f, 0.f};
    for (int k0 = 0; k0 < K; k0 += 128) {
#pragma unroll
        for (int h = 0; h < 8; ++h) {
            int ch = tid + h * 256;
            int panel = ch >> 9, within = ch & 511;
            int row = within >> 2, kq = within & 3;
            int koff = k0 + panel * 32 + kq * 8;
            __builtin_amdgcn_global_load_lds(
                (const __attribute__((address_space(1))) void*)(A + (size_t)(o0 + row) * K + koff),
                (__attribute__((address_space(3))) void*)&As[ch * 8], 16, 0, 0);
            __builtin_amdgcn_global_load_lds(
                (const __attribute__((address_space(1))) void*)(B + (size_t)(n0 + row) * K + koff),
                (__attribute__((address_space(3))) void*)&Bs[ch * 8], 16, 0, 0);
        }
        __syncthreads();
#pragma unroll
        for (int kkp = 0; kkp < 4; ++kkp) {
            short8 af[4], bfr[4];
#pragma unroll
            for (int mi = 0; mi < 4; ++mi)
                af[mi] = *(const short8*)(const void*)&As[kkp * 4096 + (wm * 64 + mi * 16 + r16) * 32 + kg * 8];
#pragma unroll
            for (int ni = 0; ni < 4; ++ni)
                bfr[ni] = *(const short8*)(const void*)&Bs[kkp * 4096 + (wn * 64 + ni * 16 + r16) * 32 + kg * 8];
#pragma unroll
            for (int mi = 0; mi < 4; ++mi)
#pragma unroll
                for (int ni = 0; ni < 4; ++ni)
                    acc[mi][ni] = __builtin_amdgcn_mfma_f32_16x16x32_bf16(af[mi], bfr[ni], acc[mi][ni], 0, 0, 0);
        }
        __syncthreads();
    }
    if (TRANS) {
#pragma unroll
        for (int mi = 0; mi < 4; ++mi) {
            int obase = o0 + wm * 64 + mi * 16 + kg * 4;
#pragma unroll
            for (int ni = 0; ni < 4; ++ni) {
                int n = n0 + wn * 64 + ni * 16 + r16;
                ushort4 pk;
                pk.x = f2bf(acc[mi][ni][0]);
                pk.y = f2bf(acc[mi][ni][1]);
                pk.z = f2bf(acc[mi][ni][2]);
                pk.w = f2bf(acc[mi][ni][3]);
                *(ushort4*)(void*)&Dt[(size_t)n * O + obase] = pk;
            }
        }
    } else {
#pragma unroll
        for (int mi = 0; mi < 4; ++mi) {
            int obase = o0 + wm * 64 + mi * 16 + kg * 4;
#pragma unroll
            for (int ni = 0; ni < 4; ++ni) {
                int col = n0 + wn * 64 + ni * 16 + r16;
#pragma unroll
                for (int r = 0; r < 4; ++r)
                    Dt[(size_t)(obase + r) * Ntot + col] = f2bf(acc[mi][ni][r]);
            }
        }
    }
    float2* red = (float2*)As;
#pragma unroll
    for (int mi = 0; mi < 4; ++mi) {
#pragma unroll
        for (int r = 0; r < 4; ++r) {
            float s = 0.f, q = 0.f;
#pragma unroll
            for (int ni = 0; ni < 4; ++ni) {
                float v = acc[mi][ni][r];
                s += v; q += v * v;
            }
#pragma unroll
            for (int off = 1; off <= 8; off <<= 1) {
                s += __shfl_xor(s, off);
                q += __shfl_xor(q, off);
            }
            if (r16 == 0) {
                int row = wm * 64 + mi * 16 + kg * 4 + r;
                red[row * 2 + wn] = make_float2(s, q);
            }
        }
    }
    __syncthreads();
    if (tid < 128) {
        float2 a = red[tid * 2 + 0], b = red[tid * 2 + 1];
        int o = o0 + tid;
        psumG[(size_t)blockIdx.x * O + o] = a.x + b.x;
        psqG [(size_t)blockIdx.x * O + o] = a.y + b.y;
    }
}

// ---------- layer1 apply: stats-reduce + BN + ReLU in place on y[N][C] bf16 ----------
__global__ __launch_bounds__(256) void bnrelu_ip_kernel(
    unsigned short* __restrict__ Y, const float* __restrict__ psumG, const float* __restrict__ psqG,
    const float* __restrict__ g, const float* __restrict__ b, int Nn, int C, int NB) {
    __shared__ float2 st[4][64];
    __shared__ float2 msr[64], gbl[64];
    int tid = threadIdx.x;
    int n0 = blockIdx.x * 64, o0 = blockIdx.y * 64;
    {
        int ch = tid & 63, q4 = tid >> 6;
        float s = 0.f, qq = 0.f;
        int per = NB / 4;
        for (int i = 0; i < per; ++i) {
            int bx = q4 * per + i;
            s  += psumG[(size_t)bx * C + o0 + ch];
            qq += psqG [(size_t)bx * C + o0 + ch];
        }
        st[q4][ch] = make_float2(s, qq);
    }
    __syncthreads();
    if (tid < 64) {
        float2 a = st[0][tid], b2 = st[1][tid], c2 = st[2][tid], d2 = st[3][tid];
        float S = (a.x + b2.x) + (c2.x + d2.x);
        float Q = (a.y + b2.y) + (c2.y + d2.y);
        float m = S / Nn;
        float v = Q / Nn - m * m;
        msr[tid] = make_float2(m, rsqrtf(v + 1e-5f));
        gbl[tid] = make_float2(g[o0 + tid], b[o0 + tid]);
    }
    __syncthreads();
    int row = tid >> 2, k0 = tid & 3;
#pragma unroll
    for (int j = 0; j < 4; ++j) {
        int k = k0 + 4 * j;
        size_t a = (size_t)(n0 + row) * C + o0 + k * 4;
        ushort4 v = *(const ushort4*)(const void*)&Y[a];
        int ob = k * 4;
        float2 ms0 = msr[ob], ms1 = msr[ob + 1], ms2 = msr[ob + 2], ms3 = msr[ob + 3];
        float2 gb0 = gbl[ob], gb1 = gbl[ob + 1], gb2 = gbl[ob + 2], gb3 = gbl[ob + 3];
        v.x = f2bf(fmaxf(gb0.x * (bf2f(v.x) - ms0.x) * ms0.y + gb0.y, 0.f));
        v.y = f2bf(fmaxf(gb1.x * (bf2f(v.y) - ms1.x) * ms1.y + gb1.y, 0.f));
        v.z = f2bf(fmaxf(gb2.x * (bf2f(v.z) - ms2.x) * ms2.y + gb2.y, 0.f));
        v.w = f2bf(fmaxf(gb3.x * (bf2f(v.w) - ms3.x) * ms3.y + gb3.y, 0.f));
        *(ushort4*)(void*)&Y[a] = v;
    }
}

// ---------- layer2 apply: stats-reduce + BN + ReLU; bf16 D [O][N] -> f32 out ----------
__global__ __launch_bounds__(256) void bnrelu2_kernel(
    const unsigned short* __restrict__ Dh, float* __restrict__ Y,
    const float* __restrict__ psumG, const float* __restrict__ psqG,
    const float* __restrict__ g, const float* __restrict__ b, int Nn, int C, int NB) {
    __shared__ float2 red[128];
    __shared__ float2 ms;
    int c = blockIdx.y, tid = threadIdx.x;
    if (tid < NB)
        red[tid] = make_float2(psumG[(size_t)tid * C + c], psqG[(size_t)tid * C + c]);
    __syncthreads();
    for (int s2 = NB / 2; s2 > 0; s2 >>= 1) {
        if (tid < s2) {
            red[tid].x += red[tid + s2].x;
            red[tid].y += red[tid + s2].y;
        }
        __syncthreads();
    }
    if (tid == 0) {
        float m = red[0].x / Nn;
        ms = make_float2(m, rsqrtf(red[0].y / Nn - m * m + 1e-5f));
    }
    __syncthreads();
    float mm = ms.x, rr = ms.y, gg = g[c], bb = b[c];
    int q = (int)blockIdx.x * 256 + tid;
    ushort4 dv = ((const ushort4*)(Dh + (size_t)c * Nn))[q];
    float4 v;
    v.x = fmaxf(gg * (bf2f(dv.x) - mm) * rr + bb, 0.f);
    v.y = fmaxf(gg * (bf2f(dv.y) - mm) * rr + bb, 0.f);
    v.z = fmaxf(gg * (bf2f(dv.z) - mm) * rr + bb, 0.f);
    v.w = fmaxf(gg * (bf2f(dv.w) - mm) * rr + bb, 0.f);
    ((float4*)Y)[(size_t)c * (Nn >> 2) + q] = v;
}

extern "C" void kernel_launch(void* const* d_in, const int* in_sizes, int n_in,
                              void* d_out, int out_size, void* d_ws, size_t ws_size,
                              hipStream_t stream) {
    const float* xyzf = (const float*)d_in[0];
    const float* xyzc = (const float*)d_in[1];
    const float* ff   = (const float*)d_in[2];
    const float* fc   = (const float*)d_in[3];
    const float* W1   = (const float*)d_in[4];
    const float* g1   = (const float*)d_in[5];
    const float* b1   = (const float*)d_in[6];
    const float* W2   = (const float*)d_in[7];
    const float* g2   = (const float*)d_in[8];
    const float* b2   = (const float*)d_in[9];

    int N  = in_sizes[0] / 3;       // 16384
    int M  = in_sizes[1] / 3;       // 4096
    int Cf = in_sizes[2] / N;       // 256
    int Cc = in_sizes[3] / M;       // 512
    int h1 = in_sizes[5];           // 512
    int h2 = in_sizes[8];           // 512
    int Cin = Cc + Cf;              // 768
    float* out = (float*)d_out;

    // workspace carve (~48 MB)
    char* p = (char*)d_ws;
    unsigned short* W1h = (unsigned short*)p; p += (size_t)h1 * Cin * 2;
    unsigned short* W2h = (unsigned short*)p; p += (size_t)h2 * h1 * 2;
    unsigned short* fcT = (unsigned short*)p; p += (size_t)M * Cc * 2;
    int*   idx3 = (int*)p;   p += (size_t)N * 3 * sizeof(int);
    float* w3   = (float*)p; p += (size_t)N * 3 * sizeof(float);
    int NB = N / 128;                                   // 128 GEMM n-blocks
    float* psumG = (float*)p; p += (size_t)NB * h1 * sizeof(float);
    float* psqG  = (float*)p; p += (size_t)NB * h1 * sizeof(float);
    unsigned short* d1h = (unsigned short*)p; p += (size_t)h1 * N * 2;   // y-layout [N][h1] bf16
    unsigned short* xbuf = (unsigned short*)p; p += (size_t)N * Cin * 2;
    // cand records alias d1h: 32B x KCH x N = 16.78 MB = exactly |d1h|.
    float4* cand = (float4*)d1h;
    unsigned short* d2h = xbuf;                         // gemm2 D [h2][N] bf16 (xbuf dead post-gemm1)

    // 1. prologue + kNN scan (1 pt/thread; prologue blocks first)
    int nW1 = h1 * Cin / 1024, nW2 = h2 * h1 / 1024;
    int Mb = M / 64, nTR = Mb * (Cc / 64);
    int nPro = nW1 + nW2 + nTR;
    scan_pro_kernel<<<nPro + (N / 256) * KCH, 256, 0, stream>>>(
        W1, W2, W1h, W2h, fc, fcT, xyzf, xyzc, cand,
        N, M, Cc, nW1, nW2, nTR, Mb);

    // 2. merge + tr_ff (independent; merge blocks first)
    int nMerge = N / 256, Nb = N / 64, nTF = Nb * (Cf / 64);
    merge_trff_kernel<<<nMerge + nTF, 256, 0, stream>>>(
        cand, xyzf, xyzc, ff, xbuf, idx3, w3, N, M, Cin, Cc, nMerge, Nb);

    // 3. interp (8 channels/thread; 4 points/block)
    interp_kernel<<<N / 4, 256, 0, stream>>>(fcT, idx3, w3, xbuf, Cin, Cc);

    // 4-5. layer 1: gemm1 writes y-layout [N][h1] into d1h; bn1 in place
    gemm_bf16_kernel<1><<<dim3(N / 128, h1 / 128), 256, 0, stream>>>(
        W1h, xbuf, d1h, psumG, psqG, Cin, N, h1);
    bnrelu_ip_kernel<<<dim3(N / 64, h1 / 64), 256, 0, stream>>>(
        d1h, psumG, psqG, g1, b1, N, h1, NB);

    // 6-7. layer 2: gemm2 reads d1h as B, writes [h2][N] into xbuf; bn2 -> out
    gemm_bf16_kernel<0><<<dim3(N / 128, h2 / 128), 256, 0, stream>>>(
        W2h, d1h, d2h, psumG, psqG, h1, N, h2);
    bnrelu2_kernel<<<dim3(N / 1024, h2), 256, 0, stream>>>(
        d2h, out, psumG, psqG, g2, b2, N, h2, NB);
}